// Round 7
// baseline (534.542 us; speedup 1.0000x reference)
//
#include <hip/hip_runtime.h>

// ============================================================================
// Mask_Oneshot_Layer: ProbMask -> RescaleProbMap -> threefry threshold mask ->
// FFT2 -> mask-multiply -> iFFT2 -> complex abs.
//
// Bit-exactness strategy:
//  * threefry2x32 partitionable semantics (CONFIRMED r2): subkey = block(0,1),
//    bits[i] = w0 ^ w1 of block(key,(0,i)).
//  * sigmoid = 1/(1+exp(-x)); exp = modern Eigen pexp_float (ILP + FMA).
//    (r4: sigmoid ulp choice moves S by <0.01 ulp -> frozen.)
//  * xbar: r5 showed horiz order is NOT the residual (bit-identical out for
//    AVX2/AVX512 folds). New: XLA hoists the batch broadcast out of the
//    reduce (0*x folded, reduce(broadcast(y)) -> 64*reduce(y), *64 exact):
//    S = VF32-strided sum over the 65536 sigmoid values, xbar = S/65536.
//    XBAR_MODE 0 = hoisted 65536-sum (this round) | 1 = 64-rep 4.19M sum (r4/r5).
// ============================================================================

#define XBAR_MODE 0
#define HORIZ_MODE 1
#define HW_N   65536
#define TOT_N  4194304u

// ---------- strict (non-contracted, non-reassociated) f32 ops ----------
__device__ __forceinline__ float f_add(float a, float b){ float d; asm("v_add_f32 %0, %1, %2" : "=v"(d) : "v"(a), "v"(b)); return d; }
__device__ __forceinline__ float f_sub(float a, float b){ float d; asm("v_sub_f32 %0, %1, %2" : "=v"(d) : "v"(a), "v"(b)); return d; }
__device__ __forceinline__ float f_mul(float a, float b){ float d; asm("v_mul_f32 %0, %1, %2" : "=v"(d) : "v"(a), "v"(b)); return d; }
__device__ __forceinline__ float f_fma(float a, float b, float c){ return __builtin_fmaf(a, b, c); }

// ---------- modern Eigen pexp_float (ILP + FMA), as XLA:CPU vectorizes ----
__device__ float xla_expf(float x0) {
  float x = fminf(x0, 88.723f);
  float m = floorf(f_fma(x, 1.44269504088896341f, 0.5f));
  float r = f_fma(m, -0.693359375f, x);
  r = f_fma(m, 2.12194440e-4f, r);
  float r2 = f_mul(r, r);
  float r3 = f_mul(r2, r);
  float y  = f_fma(1.9875691500E-4f, r, 1.3981999507E-3f);
  float y1 = f_fma(4.1665795894E-2f, r, 1.6666665459E-1f);
  float y2 = f_add(r, 1.0f);
  y  = f_fma(y, r, 8.3334519073E-3f);
  y1 = f_fma(y1, r, 5.0000001201E-1f);
  y  = f_fma(y, r3, y1);
  y  = f_fma(y, r2, y2);
  float p2n = __uint_as_float((unsigned)(((int)m + 127) << 23));
  float res = f_mul(y, p2n);
  if (x0 < -104.0f) res = 0.0f;
  return fmaxf(res, x0);
}

__device__ __forceinline__ float xla_sigmoid(float q) {
  float e = xla_expf(-q);
  return 1.0f / f_add(1.0f, e);
}

// ---------- threefry2x32 (JAX rounds) ----------
__host__ __device__ __forceinline__ void tf2x32(unsigned k0, unsigned k1,
                                                unsigned c0, unsigned c1,
                                                unsigned& o0, unsigned& o1) {
  unsigned ks2 = k0 ^ k1 ^ 0x1BD11BDAu;
  unsigned x0 = c0 + k0, x1 = c1 + k1;
#define TF_R(r) { x0 += x1; x1 = (x1 << r) | (x1 >> (32 - r)); x1 ^= x0; }
  TF_R(13) TF_R(15) TF_R(26) TF_R(6)
  x0 += k1;  x1 += ks2 + 1u;
  TF_R(17) TF_R(29) TF_R(16) TF_R(24)
  x0 += ks2; x1 += k0 + 2u;
  TF_R(13) TF_R(15) TF_R(26) TF_R(6)
  x0 += k0;  x1 += k1 + 3u;
  TF_R(17) TF_R(29) TF_R(16) TF_R(24)
  x0 += k1;  x1 += ks2 + 4u;
  TF_R(13) TF_R(15) TF_R(26) TF_R(6)
  x0 += ks2; x1 += k0 + 5u;
#undef TF_R
  o0 = x0; o1 = x1;
}

// ============================================================================
// Kernel 1: prob1 = sigmoid(5*w); also 128-entry twiddle table.
// ws floats: [0,65536) prob1 | [65536,131072) prob2 |
//            [131072,131328) twiddle | [131328..) scalars
// ============================================================================
__global__ void k_prep(const float* __restrict__ weight, float* __restrict__ ws) {
  int i = blockIdx.x * 256 + threadIdx.x;
  if (i < HW_N) {
    float q = f_mul(5.0f, weight[i]);    // PMASK_SLOPE * (0*x + w)
    ws[i] = xla_sigmoid(q);
  }
  if (blockIdx.x == 0 && threadIdx.x < 128) {
    double ang = -2.0 * 3.14159265358979323846 * (double)threadIdx.x / 256.0;
    float* tw = ws + 2 * HW_N;
    tw[2 * threadIdx.x]     = (float)cos(ang);
    tw[2 * threadIdx.x + 1] = (float)sin(ang);
  }
}

// ============================================================================
// Kernel 2: XLA:CPU EmitVectorizedReduce emulation, VF=32 strided lanes.
// XBAR_MODE 0: reduce the 65536-element prob1 block once (broadcast hoisted:
//   reduce(broadcast(y,64)) -> 64*reduce(y); *64 and /2^22 exact -> /65536).
// XBAR_MODE 1: 64-rep 4.19M-element sum (no hoisting).
// Horizontal: native-width shard left-fold + halving shuffle tree.
// ============================================================================
__global__ void k_xbar(float* __restrict__ ws) {
  __shared__ float lanes[32];
  int l = threadIdx.x;
  if (l < 32) {
    float acc = 0.0f;
#if XBAR_MODE == 0
    for (int k = 0; k < 2048; ++k)
      acc = f_add(acc, ws[32 * k + l]);
#else
    for (int rep = 0; rep < 64; ++rep)
      for (int k = 0; k < 2048; ++k)
        acc = f_add(acc, ws[32 * k + l]);
#endif
    lanes[l] = acc;
  }
  __syncthreads();
  if (l == 0) {
    float A[32];
    for (int i = 0; i < 32; ++i) A[i] = lanes[i];
    float S;
#if HORIZ_MODE == 0
    // AVX2: 4 shards of 8 (left fold), then halving shuffle tree on 8.
    float c[8];
    for (int k = 0; k < 8; ++k)
      c[k] = f_add(f_add(f_add(A[k], A[k + 8]), A[k + 16]), A[k + 24]);
    float e[4];
    for (int k = 0; k < 4; ++k) e[k] = f_add(c[k], c[k + 4]);
    float f2[2];
    for (int k = 0; k < 2; ++k) f2[k] = f_add(e[k], e[k + 2]);
    S = f_add(f2[0], f2[1]);
#else
    // AVX512: 2 shards of 16 (left fold), then halving shuffle tree on 16.
    float c[16];
    for (int k = 0; k < 16; ++k) c[k] = f_add(A[k], A[k + 16]);
    float d[8];
    for (int k = 0; k < 8; ++k)  d[k] = f_add(c[k], c[k + 8]);
    float e[4];
    for (int k = 0; k < 4; ++k)  e[k] = f_add(d[k], d[k + 4]);
    float f2[2];
    for (int k = 0; k < 2; ++k)  f2[k] = f_add(e[k], e[k + 2]);
    S = f_add(f2[0], f2[1]);
#endif
#if XBAR_MODE == 0
    float xbar = S / 65536.0f;                    // == 64*S / 2^22, both exact
#else
    float xbar = S / 4194304.0f;                  // /2^22 exact
#endif
    float r    = 0.125f / xbar;
    float le   = (r < 1.0f) ? 1.0f : 0.0f;
    float beta = 0.875f / f_sub(1.0f, xbar);
    float* sc = ws + 2 * HW_N + 256;
    sc[0] = r; sc[1] = le; sc[2] = beta;
  }
}

// ============================================================================
// Kernel 3: prob2, exact reference op order.
// ============================================================================
__global__ void k_prob2(float* __restrict__ ws) {
  int i = blockIdx.x * 256 + threadIdx.x;
  if (i >= HW_N) return;
  const float* sc = ws + 2 * HW_N + 256;
  float r = sc[0], le = sc[1], beta = sc[2];
  float p = ws[i];
  float t1 = f_mul(f_mul(le, p), r);                       // (le*p)*r
  float t2 = f_mul(f_sub(1.0f, le),
                   f_sub(1.0f, f_mul(f_sub(1.0f, p), beta)));
  ws[HW_N + i] = f_add(t1, t2);
}

// ============================================================================
// Kernel 4: threefry draw (partitionable, bits = w0^w1) + threshold -> mask.
// ============================================================================
__global__ void k_mask(const float* __restrict__ ws, float* __restrict__ mask,
                       unsigned sk0, unsigned sk1) {
  unsigned i = blockIdx.x * 256u + threadIdx.x;
  unsigned o0, o1;
  tf2x32(sk0, sk1, 0u, i, o0, o1);                // counter (hi=0, lo=i)
  unsigned bits = o0 ^ o1;
  float f = __uint_as_float((bits >> 9) | 0x3f800000u) - 1.0f;
  float p2 = ws[HW_N + (i & 65535u)];
  mask[i] = (p2 > f) ? 1.0f : 0.0f;
}

// ============================================================================
// 256-point iterative DIT FFT on LDS line (128 butterfly lanes per line).
// ============================================================================
__device__ __forceinline__ int brev8(int i) { return (int)(__brev((unsigned)i) >> 24); }

__device__ __forceinline__ void fft256(float* re, float* im, int k,
                                       const float* __restrict__ tw, float sgn) {
  for (int s = 1; s <= 8; ++s) {
    __syncthreads();
    int hm = 1 << (s - 1);
    int j  = k & (hm - 1);
    int i1 = ((k >> (s - 1)) << s) + j;
    int i2 = i1 + hm;
    int ti = j << (8 - s);
    float wr = tw[2 * ti], wi = sgn * tw[2 * ti + 1];
    float vr = re[i2], vi = im[i2];
    float tr  = vr * wr - vi * wi;
    float tii = vr * wi + vi * wr;
    float ur = re[i1], ui = im[i1];
    re[i1] = ur + tr;  im[i1] = ui + tii;
    re[i2] = ur - tr;  im[i2] = ui - tii;
  }
  __syncthreads();
}

__global__ void k_fft_row(const float* __restrict__ x, float* __restrict__ fft,
                          const float* __restrict__ ws) {
  __shared__ float re[2][256], im[2][256];
  const float* tw = ws + 2 * HW_N;
  int line = blockIdx.x * 2 + (threadIdx.x >> 7);   // b*256 + h
  int k = threadIdx.x & 127, r = threadIdx.x >> 7;
  int b = line >> 8, h = line & 255;
  const float* src = x + b * 65536 + h * 256;
  re[r][k]       = src[brev8(k)];        im[r][k]       = 0.0f;
  re[r][k + 128] = src[brev8(k + 128)];  im[r][k + 128] = 0.0f;
  fft256(re[r], im[r], k, tw, 1.0f);
  float* dre = fft + b * 131072 + h * 256;
  float* dim = dre + 65536;
  dre[k]       = re[r][k];        dim[k]       = im[r][k];
  dre[k + 128] = re[r][k + 128];  dim[k + 128] = im[r][k + 128];
}

__global__ void k_fft_col(float* __restrict__ fft, const float* __restrict__ mask,
                          float* __restrict__ uk, const float* __restrict__ ws) {
  __shared__ float re[2][256], im[2][256];
  const float* tw = ws + 2 * HW_N;
  int line = blockIdx.x * 2 + (threadIdx.x >> 7);   // b*256 + c
  int k = threadIdx.x & 127, r = threadIdx.x >> 7;
  int b = line >> 8, c = line & 255;
  float* pre = fft + b * 131072;
  float* pim = pre + 65536;
  {
    int s0 = brev8(k), s1 = brev8(k + 128);
    re[r][k]       = pre[s0 * 256 + c];  im[r][k]       = pim[s0 * 256 + c];
    re[r][k + 128] = pre[s1 * 256 + c];  im[r][k + 128] = pim[s1 * 256 + c];
  }
  fft256(re[r], im[r], k, tw, 1.0f);
  const float* mk = mask + b * 65536;
  float* ukre = uk + b * 131072;
  float* ukim = ukre + 65536;
  for (int t = 0; t < 2; ++t) {
    int i = k + t * 128;
    float vr = re[r][i], vi = im[r][i];
    pre[i * 256 + c] = vr;  pim[i * 256 + c] = vi;
    float m = mk[i * 256 + c];
    ukre[i * 256 + c] = vr * m;
    ukim[i * 256 + c] = vi * m;
  }
}

__global__ void k_ifft_row(const float* __restrict__ uk, float* __restrict__ uif,
                           const float* __restrict__ ws) {
  __shared__ float re[2][256], im[2][256];
  const float* tw = ws + 2 * HW_N;
  int line = blockIdx.x * 2 + (threadIdx.x >> 7);   // b*256 + h
  int k = threadIdx.x & 127, r = threadIdx.x >> 7;
  int b = line >> 8, h = line & 255;
  const float* sre = uk + b * 131072 + h * 256;
  const float* sim = sre + 65536;
  re[r][k]       = sre[brev8(k)];        im[r][k]       = sim[brev8(k)];
  re[r][k + 128] = sre[brev8(k + 128)];  im[r][k + 128] = sim[brev8(k + 128)];
  fft256(re[r], im[r], k, tw, -1.0f);
  float* dre = uif + b * 131072 + h * 256;
  float* dim = dre + 65536;
  dre[k]       = re[r][k];        dim[k]       = im[r][k];
  dre[k + 128] = re[r][k + 128];  dim[k + 128] = im[r][k + 128];
}

__global__ void k_ifft_col(float* __restrict__ uif, float* __restrict__ cabs,
                           const float* __restrict__ ws) {
  __shared__ float re[2][256], im[2][256];
  const float* tw = ws + 2 * HW_N;
  int line = blockIdx.x * 2 + (threadIdx.x >> 7);   // b*256 + c
  int k = threadIdx.x & 127, r = threadIdx.x >> 7;
  int b = line >> 8, c = line & 255;
  float* pre = uif + b * 131072;
  float* pim = pre + 65536;
  {
    int s0 = brev8(k), s1 = brev8(k + 128);
    re[r][k]       = pre[s0 * 256 + c];  im[r][k]       = pim[s0 * 256 + c];
    re[r][k + 128] = pre[s1 * 256 + c];  im[r][k + 128] = pim[s1 * 256 + c];
  }
  fft256(re[r], im[r], k, tw, -1.0f);
  const float scale = 1.0f / 65536.0f;
  float* ab = cabs + b * 65536;
  for (int t = 0; t < 2; ++t) {
    int i = k + t * 128;
    float vr = re[r][i] * scale, vi = im[r][i] * scale;
    pre[i * 256 + c] = vr;  pim[i * 256 + c] = vi;
    ab[i * 256 + c] = sqrtf(vr * vr + vi * vi);
  }
}

// ============================================================================
extern "C" void kernel_launch(void* const* d_in, const int* in_sizes, int n_in,
                              void* d_out, int out_size, void* d_ws, size_t ws_size,
                              hipStream_t stream) {
  const float* x      = (const float*)d_in[0];   // [64,1,256,256] f32
  const float* weight = (const float*)d_in[1];   // [1,1,256,256]  f32
  float* out = (float*)d_out;
  float* ws  = (float*)d_ws;

  float* uifft = out;                  // [64,2,256,256]
  float* cabs  = out + 8388608;        // [64,1,256,256]
  float* mask  = out + 12582912;       // [64,1,256,256]
  float* fft   = out + 16777216;       // [64,2,256,256]
  float* uk    = out + 25165824;       // [64,2,256,256]

  // sub-key = jax.random.split(key(42))[1] (partitionable): block(0,1).
  unsigned sk0, sk1;
  tf2x32(0u, 42u, 0u, 1u, sk0, sk1);

  k_prep <<<256, 256, 0, stream>>>(weight, ws);
  k_xbar <<<1, 64, 0, stream>>>(ws);
  k_prob2<<<256, 256, 0, stream>>>(ws);
  k_mask <<<16384, 256, 0, stream>>>(ws, mask, sk0, sk1);
  k_fft_row <<<8192, 256, 0, stream>>>(x, fft, ws);
  k_fft_col <<<8192, 256, 0, stream>>>(fft, mask, uk, ws);
  k_ifft_row<<<8192, 256, 0, stream>>>(uk, uifft, ws);
  k_ifft_col<<<8192, 256, 0, stream>>>(uifft, cabs, ws);
}

// Round 8
// 279.305 us; speedup vs baseline: 1.9138x; 1.9138x over previous
//
#include <hip/hip_runtime.h>

// ============================================================================
// Mask_Oneshot_Layer — PASSED r7 (absmax 2.0). Bit-exact parts FROZEN:
//  * threefry partitionable: subkey = block(0,1); bits = w0^w1.
//  * sigmoid = 1/(1+exp(-x)), Eigen FMA pexp.
//  * xbar: broadcast-hoisted VF=32 strided sum over 65536, AVX512 horiz.
// r8 optimization: column passes were 5x over-fetch (strided). New tiled
// colpass: 32 cols x 256 rows in 64KB LDS, DIF fwd (nat in, bitrev out) ->
// mask-mult -> DIT inv (bitrev in, nat out) fused; row-inverse + cabs fused.
// ============================================================================

#define HW_N   65536

// ---------- strict (non-contracted, non-reassociated) f32 ops ----------
__device__ __forceinline__ float f_add(float a, float b){ float d; asm("v_add_f32 %0, %1, %2" : "=v"(d) : "v"(a), "v"(b)); return d; }
__device__ __forceinline__ float f_sub(float a, float b){ float d; asm("v_sub_f32 %0, %1, %2" : "=v"(d) : "v"(a), "v"(b)); return d; }
__device__ __forceinline__ float f_mul(float a, float b){ float d; asm("v_mul_f32 %0, %1, %2" : "=v"(d) : "v"(a), "v"(b)); return d; }
__device__ __forceinline__ float f_fma(float a, float b, float c){ return __builtin_fmaf(a, b, c); }

// ---------- Eigen pexp_float (ILP + FMA) ----------
__device__ float xla_expf(float x0) {
  float x = fminf(x0, 88.723f);
  float m = floorf(f_fma(x, 1.44269504088896341f, 0.5f));
  float r = f_fma(m, -0.693359375f, x);
  r = f_fma(m, 2.12194440e-4f, r);
  float r2 = f_mul(r, r);
  float r3 = f_mul(r2, r);
  float y  = f_fma(1.9875691500E-4f, r, 1.3981999507E-3f);
  float y1 = f_fma(4.1665795894E-2f, r, 1.6666665459E-1f);
  float y2 = f_add(r, 1.0f);
  y  = f_fma(y, r, 8.3334519073E-3f);
  y1 = f_fma(y1, r, 5.0000001201E-1f);
  y  = f_fma(y, r3, y1);
  y  = f_fma(y, r2, y2);
  float p2n = __uint_as_float((unsigned)(((int)m + 127) << 23));
  float res = f_mul(y, p2n);
  if (x0 < -104.0f) res = 0.0f;
  return fmaxf(res, x0);
}

__device__ __forceinline__ float xla_sigmoid(float q) {
  float e = xla_expf(-q);
  return 1.0f / f_add(1.0f, e);
}

// ---------- threefry2x32 ----------
__host__ __device__ __forceinline__ void tf2x32(unsigned k0, unsigned k1,
                                                unsigned c0, unsigned c1,
                                                unsigned& o0, unsigned& o1) {
  unsigned ks2 = k0 ^ k1 ^ 0x1BD11BDAu;
  unsigned x0 = c0 + k0, x1 = c1 + k1;
#define TF_R(r) { x0 += x1; x1 = (x1 << r) | (x1 >> (32 - r)); x1 ^= x0; }
  TF_R(13) TF_R(15) TF_R(26) TF_R(6)
  x0 += k1;  x1 += ks2 + 1u;
  TF_R(17) TF_R(29) TF_R(16) TF_R(24)
  x0 += ks2; x1 += k0 + 2u;
  TF_R(13) TF_R(15) TF_R(26) TF_R(6)
  x0 += k0;  x1 += k1 + 3u;
  TF_R(17) TF_R(29) TF_R(16) TF_R(24)
  x0 += k1;  x1 += ks2 + 4u;
  TF_R(13) TF_R(15) TF_R(26) TF_R(6)
  x0 += ks2; x1 += k0 + 5u;
#undef TF_R
  o0 = x0; o1 = x1;
}

// ============================================================================
// Kernel 1: prob1 = sigmoid(5*w); twiddle table tw[i] = e^{-2pi i/256}, i<128.
// ws floats: [0,65536) prob1 | [65536,131072) prob2 | [131072,131328) tw |
//            [131328..) scalars
// ============================================================================
__global__ void k_prep(const float* __restrict__ weight, float* __restrict__ ws) {
  int i = blockIdx.x * 256 + threadIdx.x;
  if (i < HW_N) {
    float q = f_mul(5.0f, weight[i]);
    ws[i] = xla_sigmoid(q);
  }
  if (blockIdx.x == 0 && threadIdx.x < 128) {
    double ang = -2.0 * 3.14159265358979323846 * (double)threadIdx.x / 256.0;
    float* tw = ws + 2 * HW_N;
    tw[2 * threadIdx.x]     = (float)cos(ang);
    tw[2 * threadIdx.x + 1] = (float)sin(ang);
  }
}

// ============================================================================
// Kernel 2: hoisted VF=32 strided reduce (FROZEN, verified r7).
// ============================================================================
__global__ void k_xbar(float* __restrict__ ws) {
  __shared__ float lanes[32];
  int l = threadIdx.x;
  if (l < 32) {
    float acc = 0.0f;
    for (int k = 0; k < 2048; ++k)
      acc = f_add(acc, ws[32 * k + l]);
    lanes[l] = acc;
  }
  __syncthreads();
  if (l == 0) {
    float A[32];
    for (int i = 0; i < 32; ++i) A[i] = lanes[i];
    float c[16];
    for (int k = 0; k < 16; ++k) c[k] = f_add(A[k], A[k + 16]);
    float d[8];
    for (int k = 0; k < 8; ++k)  d[k] = f_add(c[k], c[k + 8]);
    float e[4];
    for (int k = 0; k < 4; ++k)  e[k] = f_add(d[k], d[k + 4]);
    float f2[2];
    for (int k = 0; k < 2; ++k)  f2[k] = f_add(e[k], e[k + 2]);
    float S = f_add(f2[0], f2[1]);
    float xbar = S / 65536.0f;
    float r    = 0.125f / xbar;
    float le   = (r < 1.0f) ? 1.0f : 0.0f;
    float beta = 0.875f / f_sub(1.0f, xbar);
    float* sc = ws + 2 * HW_N + 256;
    sc[0] = r; sc[1] = le; sc[2] = beta;
  }
}

// ============================================================================
// Kernel 3: prob2 (FROZEN).
// ============================================================================
__global__ void k_prob2(float* __restrict__ ws) {
  int i = blockIdx.x * 256 + threadIdx.x;
  if (i >= HW_N) return;
  const float* sc = ws + 2 * HW_N + 256;
  float r = sc[0], le = sc[1], beta = sc[2];
  float p = ws[i];
  float t1 = f_mul(f_mul(le, p), r);
  float t2 = f_mul(f_sub(1.0f, le),
                   f_sub(1.0f, f_mul(f_sub(1.0f, p), beta)));
  ws[HW_N + i] = f_add(t1, t2);
}

// ============================================================================
// Kernel 4: threefry mask (FROZEN).
// ============================================================================
__global__ void k_mask(const float* __restrict__ ws, float* __restrict__ mask,
                       unsigned sk0, unsigned sk1) {
  unsigned i = blockIdx.x * 256u + threadIdx.x;
  unsigned o0, o1;
  tf2x32(sk0, sk1, 0u, i, o0, o1);
  unsigned bits = o0 ^ o1;
  float f = __uint_as_float((bits >> 9) | 0x3f800000u) - 1.0f;
  float p2 = ws[HW_N + (i & 65535u)];
  mask[i] = (p2 > f) ? 1.0f : 0.0f;
}

// ============================================================================
// Row FFT helpers (2 lines per 256-thread block, 128 butterfly lanes/line).
// DIT: input placed bit-reversed in LDS, natural-order output.
// ============================================================================
__device__ __forceinline__ int brev8(int i) { return (int)(__brev((unsigned)i) >> 24); }

__device__ __forceinline__ void fft256(float* re, float* im, int k,
                                       const float* __restrict__ tw, float sgn) {
  for (int s = 1; s <= 8; ++s) {
    __syncthreads();
    int hm = 1 << (s - 1);
    int j  = k & (hm - 1);
    int i1 = ((k >> (s - 1)) << s) + j;
    int i2 = i1 + hm;
    int ti = j << (8 - s);
    float wr = tw[2 * ti], wi = sgn * tw[2 * ti + 1];
    float vr = re[i2], vi = im[i2];
    float tr  = vr * wr - vi * wi;
    float tii = vr * wi + vi * wr;
    float ur = re[i1], ui = im[i1];
    re[i1] = ur + tr;  im[i1] = ui + tii;
    re[i2] = ur - tr;  im[i2] = ui - tii;
  }
  __syncthreads();
}

// Forward rows: x (real) -> rowfft planes (natural order within row).
__global__ void k_fft_row(const float* __restrict__ x, float* __restrict__ fft,
                          const float* __restrict__ ws) {
  __shared__ float re[2][256], im[2][256];
  const float* tw = ws + 2 * HW_N;
  int line = blockIdx.x * 2 + (threadIdx.x >> 7);   // b*256 + h
  int k = threadIdx.x & 127, r = threadIdx.x >> 7;
  int b = line >> 8, h = line & 255;
  const float* src = x + b * 65536 + h * 256;
  re[r][k]       = src[brev8(k)];        im[r][k]       = 0.0f;
  re[r][k + 128] = src[brev8(k + 128)];  im[r][k + 128] = 0.0f;
  fft256(re[r], im[r], k, tw, 1.0f);
  float* dre = fft + b * 131072 + h * 256;
  float* dim = dre + 65536;
  dre[k]       = re[r][k];        dim[k]       = im[r][k];
  dre[k + 128] = re[r][k + 128];  dim[k + 128] = im[r][k + 128];
}

// ============================================================================
// Tiled column pass: per block = 1 image x 32-column tile x all 256 rows.
// LDS 64KB, bank-swizzle (c+r)&31 -> conflict-free loads & butterflies.
//  phase A: coalesced load (128B row segments)
//  phase B: forward column FFT, DIF (natural in, bit-rev out)
//  phase C: write fft output rows (freq = brev(pos)), read mask, write uk,
//           keep masked values in LDS
//  phase D: inverse column FFT, DIT (bit-rev in, natural out)
//  phase E: write v rows (spatial) into vbuf (= uifft slot, scratch)
// ============================================================================
__global__ __launch_bounds__(256) void k_colpass(float* __restrict__ fftbuf,
                                                 const float* __restrict__ mask,
                                                 float* __restrict__ uk,
                                                 float* __restrict__ vbuf,
                                                 const float* __restrict__ ws) {
  __shared__ float lre[256][32];
  __shared__ float lim[256][32];
  const float* tw = ws + 2 * HW_N;
  int bid = blockIdx.x;
  int b = bid >> 3, c0 = (bid & 7) << 5;
  int t = threadIdx.x;
  int cl = t & 31, rg = t >> 5;                 // col-in-tile, row-group 0..7
  float* pre = fftbuf + b * 131072;
  float* pim = pre + 65536;

  // A: load
  for (int it = 0; it < 32; ++it) {
    int r = (it << 3) + rg;
    int cc = (cl + r) & 31;
    lre[r][cc] = pre[r * 256 + c0 + cl];
    lim[r][cc] = pim[r * 256 + c0 + cl];
  }
  __syncthreads();

  // B: forward DIF over the 256 rows of each column
  for (int hm = 128, sh = 7; hm >= 1; hm >>= 1, --sh) {
    for (int kk = 0; kk < 16; ++kk) {
      int k = (kk << 3) + rg;                   // 0..127
      int j = k & (hm - 1);
      int i1 = ((k >> sh) << (sh + 1)) + j;
      int i2 = i1 + hm;
      int ti = j << (7 - sh);                   // j * (128/hm)
      float wr = tw[2 * ti], wi = tw[2 * ti + 1];
      int cc1 = (cl + i1) & 31, cc2 = (cl + i2) & 31;
      float ur = lre[i1][cc1], ui = lim[i1][cc1];
      float vr = lre[i2][cc2], vi = lim[i2][cc2];
      float dr = ur - vr, di = ui - vi;
      lre[i1][cc1] = ur + vr;            lim[i1][cc1] = ui + vi;
      lre[i2][cc2] = dr * wr - di * wi;  lim[i2][cc2] = dr * wi + di * wr;
    }
    __syncthreads();
  }

  // C: fft out + mask + uk out (array pos p holds frequency brev(p))
  const float* mk = mask + b * 65536;
  float* ukre = uk + b * 131072;
  float* ukim = ukre + 65536;
  for (int it = 0; it < 32; ++it) {
    int p = (it << 3) + rg;
    int f = brev8(p);
    int cc = (cl + p) & 31;
    float vr = lre[p][cc], vi = lim[p][cc];
    int gi = f * 256 + c0 + cl;
    pre[gi] = vr;  pim[gi] = vi;
    float m = mk[gi];
    float mvr = vr * m, mvi = vi * m;
    ukre[gi] = mvr;  ukim[gi] = mvi;
    lre[p][cc] = mvr;  lim[p][cc] = mvi;
  }
  __syncthreads();

  // D: inverse DIT (bit-rev input in array, natural output), conj twiddles
  for (int s = 1; s <= 8; ++s) {
    int hm = 1 << (s - 1);
    for (int kk = 0; kk < 16; ++kk) {
      int k = (kk << 3) + rg;
      int j = k & (hm - 1);
      int i1 = ((k >> (s - 1)) << s) + j;
      int i2 = i1 + hm;
      int ti = j << (8 - s);
      float wr = tw[2 * ti], wi = -tw[2 * ti + 1];
      int cc1 = (cl + i1) & 31, cc2 = (cl + i2) & 31;
      float vr = lre[i2][cc2], vi = lim[i2][cc2];
      float tr = vr * wr - vi * wi, tii = vr * wi + vi * wr;
      float ur = lre[i1][cc1], ui = lim[i1][cc1];
      lre[i1][cc1] = ur + tr;  lim[i1][cc1] = ui + tii;
      lre[i2][cc2] = ur - tr;  lim[i2][cc2] = ui - tii;
    }
    __syncthreads();
  }

  // E: write v (spatial rows)
  float* vre = vbuf + b * 131072;
  float* vim = vre + 65536;
  for (int it = 0; it < 32; ++it) {
    int r = (it << 3) + rg;
    int cc = (cl + r) & 31;
    vre[r * 256 + c0 + cl] = lre[r][cc];
    vim[r * 256 + c0 + cl] = lim[r][cc];
  }
}

// ============================================================================
// Final: row inverse FFT (in-place on uifft slot holding v), scale 1/65536,
// write uifft + complex_abs.
// ============================================================================
__global__ void k_irow(float* __restrict__ uif, float* __restrict__ cabs,
                       const float* __restrict__ ws) {
  __shared__ float re[2][256], im[2][256];
  const float* tw = ws + 2 * HW_N;
  int line = blockIdx.x * 2 + (threadIdx.x >> 7);   // b*256 + h
  int k = threadIdx.x & 127, r = threadIdx.x >> 7;
  int b = line >> 8, h = line & 255;
  float* sre = uif + b * 131072 + h * 256;
  float* sim = sre + 65536;
  re[r][k]       = sre[brev8(k)];        im[r][k]       = sim[brev8(k)];
  re[r][k + 128] = sre[brev8(k + 128)];  im[r][k + 128] = sim[brev8(k + 128)];
  fft256(re[r], im[r], k, tw, -1.0f);
  const float scale = 1.0f / 65536.0f;
  float* ab = cabs + b * 65536 + h * 256;
  for (int t2 = 0; t2 < 2; ++t2) {
    int i = k + t2 * 128;
    float vr = re[r][i] * scale, vi = im[r][i] * scale;
    sre[i] = vr;  sim[i] = vi;
    ab[i] = sqrtf(vr * vr + vi * vi);
  }
}

// ============================================================================
extern "C" void kernel_launch(void* const* d_in, const int* in_sizes, int n_in,
                              void* d_out, int out_size, void* d_ws, size_t ws_size,
                              hipStream_t stream) {
  const float* x      = (const float*)d_in[0];   // [64,1,256,256] f32
  const float* weight = (const float*)d_in[1];   // [1,1,256,256]  f32
  float* out = (float*)d_out;
  float* ws  = (float*)d_ws;

  float* uifft = out;                  // [64,2,256,256] (also v scratch)
  float* cabs  = out + 8388608;        // [64,1,256,256]
  float* mask  = out + 12582912;       // [64,1,256,256]
  float* fft   = out + 16777216;       // [64,2,256,256]
  float* uk    = out + 25165824;       // [64,2,256,256]

  // sub-key = jax.random.split(key(42))[1] (partitionable): block(0,1).
  unsigned sk0, sk1;
  tf2x32(0u, 42u, 0u, 1u, sk0, sk1);

  k_prep   <<<256, 256, 0, stream>>>(weight, ws);
  k_xbar   <<<1, 64, 0, stream>>>(ws);
  k_prob2  <<<256, 256, 0, stream>>>(ws);
  k_mask   <<<16384, 256, 0, stream>>>(ws, mask, sk0, sk1);
  k_fft_row<<<8192, 256, 0, stream>>>(x, fft, ws);
  k_colpass<<<512, 256, 0, stream>>>(fft, mask, uk, uifft, ws);
  k_irow   <<<8192, 256, 0, stream>>>(uifft, cabs, ws);
}

// Round 10
// 274.550 us; speedup vs baseline: 1.9470x; 1.0173x over previous
//
#include <hip/hip_runtime.h>

// ============================================================================
// Mask_Oneshot_Layer — r10 (= r9 kernel, resubmitted after broker timeout).
// Bit-exact parts FROZEN (r7):
//  * threefry partitionable: subkey = block(0,1); bits = w0^w1.
//  * sigmoid = 1/(1+exp(-x)), Eigen FMA pexp.
//  * xbar: broadcast-hoisted VF=32 strided sum over 65536, AVX512 horiz.
//  * prob2 strict-op sequence (inlined in k_mask — same bits).
// r9/r10: radix-4 FFTs (half the LDS ops & syncs of r8's radix-2), rev4 digit
// reversal, LDS index map a+(a>>5) for row kernels, k_prob2 folded into
// k_mask, 256-entry twiddle table.
// ============================================================================

#define HW_N 65536
#define LMAP(a) ((a) + ((a) >> 5))   // row-kernel LDS anti-conflict map

// ---------- strict (non-contracted) f32 ops — frozen math only ----------
__device__ __forceinline__ float f_add(float a, float b){ float d; asm("v_add_f32 %0, %1, %2" : "=v"(d) : "v"(a), "v"(b)); return d; }
__device__ __forceinline__ float f_sub(float a, float b){ float d; asm("v_sub_f32 %0, %1, %2" : "=v"(d) : "v"(a), "v"(b)); return d; }
__device__ __forceinline__ float f_mul(float a, float b){ float d; asm("v_mul_f32 %0, %1, %2" : "=v"(d) : "v"(a), "v"(b)); return d; }
__device__ __forceinline__ float f_fma(float a, float b, float c){ return __builtin_fmaf(a, b, c); }

// ---------- Eigen pexp_float (ILP + FMA) ----------
__device__ float xla_expf(float x0) {
  float x = fminf(x0, 88.723f);
  float m = floorf(f_fma(x, 1.44269504088896341f, 0.5f));
  float r = f_fma(m, -0.693359375f, x);
  r = f_fma(m, 2.12194440e-4f, r);
  float r2 = f_mul(r, r);
  float r3 = f_mul(r2, r);
  float y  = f_fma(1.9875691500E-4f, r, 1.3981999507E-3f);
  float y1 = f_fma(4.1665795894E-2f, r, 1.6666665459E-1f);
  float y2 = f_add(r, 1.0f);
  y  = f_fma(y, r, 8.3334519073E-3f);
  y1 = f_fma(y1, r, 5.0000001201E-1f);
  y  = f_fma(y, r3, y1);
  y  = f_fma(y, r2, y2);
  float p2n = __uint_as_float((unsigned)(((int)m + 127) << 23));
  float res = f_mul(y, p2n);
  if (x0 < -104.0f) res = 0.0f;
  return fmaxf(res, x0);
}
__device__ __forceinline__ float xla_sigmoid(float q) {
  float e = xla_expf(-q);
  return 1.0f / f_add(1.0f, e);
}

// ---------- threefry2x32 ----------
__host__ __device__ __forceinline__ void tf2x32(unsigned k0, unsigned k1,
                                                unsigned c0, unsigned c1,
                                                unsigned& o0, unsigned& o1) {
  unsigned ks2 = k0 ^ k1 ^ 0x1BD11BDAu;
  unsigned x0 = c0 + k0, x1 = c1 + k1;
#define TF_R(r) { x0 += x1; x1 = (x1 << r) | (x1 >> (32 - r)); x1 ^= x0; }
  TF_R(13) TF_R(15) TF_R(26) TF_R(6)
  x0 += k1;  x1 += ks2 + 1u;
  TF_R(17) TF_R(29) TF_R(16) TF_R(24)
  x0 += ks2; x1 += k0 + 2u;
  TF_R(13) TF_R(15) TF_R(26) TF_R(6)
  x0 += k0;  x1 += k1 + 3u;
  TF_R(17) TF_R(29) TF_R(16) TF_R(24)
  x0 += k1;  x1 += ks2 + 4u;
  TF_R(13) TF_R(15) TF_R(26) TF_R(6)
  x0 += ks2; x1 += k0 + 5u;
#undef TF_R
  o0 = x0; o1 = x1;
}

// ---------- base-4 digit reversal of 4 digits ----------
__device__ __forceinline__ int rev4(int p) {
  return ((p & 3) << 6) | (((p >> 2) & 3) << 4) | (((p >> 4) & 3) << 2) | ((p >> 6) & 3);
}

// complex *= tw[ti] (forward) / conj(tw[ti]) (inverse)
#define CMULW(xr, xi, ti) { float wr = tw[2*(ti)], wi = tw[2*(ti)+1]; \
  float nr = xr*wr - xi*wi; xi = xr*wi + xi*wr; xr = nr; }
#define CMULWC(xr, xi, ti) { float wr = tw[2*(ti)], wi = tw[2*(ti)+1]; \
  float nr = xr*wr + xi*wi; xi = xi*wr - xr*wi; xr = nr; }

// ============================================================================
// Kernel 1: prob1 = sigmoid(5*w); 256-entry twiddle table.
// ws floats: [0,65536) prob1 | [131072,131584) tw | [131584..) scalars
// ============================================================================
__global__ void k_prep(const float* __restrict__ weight, float* __restrict__ ws) {
  int i = blockIdx.x * 256 + threadIdx.x;
  if (i < HW_N) {
    float q = f_mul(5.0f, weight[i]);
    ws[i] = xla_sigmoid(q);
  }
  if (blockIdx.x == 0) {
    int t = threadIdx.x;           // 0..255
    double ang = -2.0 * 3.14159265358979323846 * (double)t / 256.0;
    float* tw = ws + 131072;
    tw[2 * t]     = (float)cos(ang);
    tw[2 * t + 1] = (float)sin(ang);
  }
}

// ============================================================================
// Kernel 2: hoisted VF=32 strided reduce (FROZEN, verified r7).
// ============================================================================
__global__ void k_xbar(float* __restrict__ ws) {
  __shared__ float lanes[32];
  int l = threadIdx.x;
  if (l < 32) {
    float acc = 0.0f;
    for (int k = 0; k < 2048; ++k)
      acc = f_add(acc, ws[32 * k + l]);
    lanes[l] = acc;
  }
  __syncthreads();
  if (l == 0) {
    float A[32];
    for (int i = 0; i < 32; ++i) A[i] = lanes[i];
    float c[16];
    for (int k = 0; k < 16; ++k) c[k] = f_add(A[k], A[k + 16]);
    float d[8];
    for (int k = 0; k < 8; ++k)  d[k] = f_add(c[k], c[k + 8]);
    float e[4];
    for (int k = 0; k < 4; ++k)  e[k] = f_add(d[k], d[k + 4]);
    float f2[2];
    for (int k = 0; k < 2; ++k)  f2[k] = f_add(e[k], e[k + 2]);
    float S = f_add(f2[0], f2[1]);
    float xbar = S / 65536.0f;
    float r    = 0.125f / xbar;
    float le   = (r < 1.0f) ? 1.0f : 0.0f;
    float beta = 0.875f / f_sub(1.0f, xbar);
    float* sc = ws + 131584;
    sc[0] = r; sc[1] = le; sc[2] = beta;
  }
}

// ============================================================================
// Kernel 3: mask = (prob2 > threefry-uniform); prob2 inlined (FROZEN op order).
// ============================================================================
__global__ void k_mask(const float* __restrict__ ws, float* __restrict__ mask,
                       unsigned sk0, unsigned sk1) {
  unsigned i = blockIdx.x * 256u + threadIdx.x;
  const float* sc = ws + 131584;
  float r = sc[0], le = sc[1], beta = sc[2];
  float p1 = ws[i & 65535u];
  float t1 = f_mul(f_mul(le, p1), r);
  float t2 = f_mul(f_sub(1.0f, le),
                   f_sub(1.0f, f_mul(f_sub(1.0f, p1), beta)));
  float p2 = f_add(t1, t2);
  unsigned o0, o1;
  tf2x32(sk0, sk1, 0u, i, o0, o1);
  unsigned bits = o0 ^ o1;
  float f = __uint_as_float((bits >> 9) | 0x3f800000u) - 1.0f;
  mask[i] = (p2 > f) ? 1.0f : 0.0f;
}

// ============================================================================
// Row forward FFT: radix-4 DIT, rev4 gather load, natural-order output.
// Block = 4 rows; wave = 1 row (64 butterfly lanes).
// ============================================================================
__global__ __launch_bounds__(256) void k_fft_row(const float* __restrict__ x,
                                                 float* __restrict__ fftb,
                                                 const float* __restrict__ ws) {
  __shared__ float re[4][264], im[4][264];
  const float* tw = ws + 131072;
  int rl = threadIdx.x >> 6, bf = threadIdx.x & 63;
  int line = blockIdx.x * 4 + rl;
  int b = line >> 8, h = line & 255;
  const float* src = x + b * 65536 + h * 256;
  float* lre = re[rl];
  float* lim = im[rl];
  #pragma unroll
  for (int t2 = 0; t2 < 4; ++t2) {
    int p = t2 * 64 + bf;
    lre[LMAP(p)] = src[rev4(p)];
    lim[LMAP(p)] = 0.0f;
  }
  #pragma unroll
  for (int s2 = 0; s2 < 4; ++s2) {
    __syncthreads();
    int lq = 2 * s2, qq = 1 << lq;
    int j = bf & (qq - 1), g = bf >> lq;
    int base = (g << (lq + 2)) + j;
    int u = 64 >> lq;
    int a0 = base, a1 = base + qq, a2 = base + 2 * qq, a3 = base + 3 * qq;
    float s0r = lre[LMAP(a0)], s0i = lim[LMAP(a0)];
    float s1r = lre[LMAP(a1)], s1i = lim[LMAP(a1)];
    float s2r = lre[LMAP(a2)], s2i = lim[LMAP(a2)];
    float s3r = lre[LMAP(a3)], s3i = lim[LMAP(a3)];
    int ti = j * u;
    CMULW(s1r, s1i, ti); CMULW(s2r, s2i, 2 * ti); CMULW(s3r, s3i, 3 * ti);
    float p0r = s0r + s2r, p0i = s0i + s2i;
    float m0r = s0r - s2r, m0i = s0i - s2i;
    float p1r = s1r + s3r, p1i = s1i + s3i;
    float m1r = s1r - s3r, m1i = s1i - s3i;
    lre[LMAP(a0)] = p0r + p1r;  lim[LMAP(a0)] = p0i + p1i;
    lre[LMAP(a1)] = m0r + m1i;  lim[LMAP(a1)] = m0i - m1r;   // m0 - i*m1
    lre[LMAP(a2)] = p0r - p1r;  lim[LMAP(a2)] = p0i - p1i;
    lre[LMAP(a3)] = m0r - m1i;  lim[LMAP(a3)] = m0i + m1r;   // m0 + i*m1
  }
  __syncthreads();
  float* dre = fftb + b * 131072 + h * 256;
  float* dim = dre + 65536;
  #pragma unroll
  for (int t2 = 0; t2 < 4; ++t2) {
    int p = t2 * 64 + bf;
    dre[p] = lre[LMAP(p)];
    dim[p] = lim[LMAP(p)];
  }
}

// ============================================================================
// Tiled column pass, radix-4: per block = 1 image x 32-col tile x 256 rows.
// A: load | B: DIF fwd (natural in, rev4 out) | C: fft/mask/uk at f=rev4(p)
// D: DIT inv (rev4 in, natural out) | E: write v.
// ============================================================================
__global__ __launch_bounds__(256) void k_colpass(float* __restrict__ fftbuf,
                                                 const float* __restrict__ mask,
                                                 float* __restrict__ uk,
                                                 float* __restrict__ vbuf,
                                                 const float* __restrict__ ws) {
  __shared__ float lre[256][32];
  __shared__ float lim[256][32];
  const float* tw = ws + 131072;
  int bid = blockIdx.x;
  int b = bid >> 3, c0 = (bid & 7) << 5;
  int t = threadIdx.x;
  int cl = t & 31, rg = t >> 5;                 // col-in-tile, row-group 0..7
  float* pre = fftbuf + b * 131072;
  float* pim = pre + 65536;

  // A: coalesced load
  for (int it = 0; it < 32; ++it) {
    int r = (it << 3) + rg;
    int cc = (cl + r) & 31;
    lre[r][cc] = pre[r * 256 + c0 + cl];
    lim[r][cc] = pim[r * 256 + c0 + cl];
  }

  // B: forward DIF radix-4 (m = 256,64,16,4)
  #pragma unroll
  for (int s2 = 0; s2 < 4; ++s2) {
    __syncthreads();
    int lq = 6 - 2 * s2, qq = 1 << lq;
    int u = 1 << (2 * s2);
    for (int kk = 0; kk < 8; ++kk) {
      int bf = (kk << 3) + rg;
      int j = bf & (qq - 1), g = bf >> lq;
      int base = (g << (lq + 2)) + j;
      int a0 = base, a1 = base + qq, a2 = base + 2 * qq, a3 = base + 3 * qq;
      int c_0 = (cl + a0) & 31, c_1 = (cl + a1) & 31,
          c_2 = (cl + a2) & 31, c_3 = (cl + a3) & 31;
      float ar = lre[a0][c_0], ai = lim[a0][c_0];
      float br = lre[a1][c_1], bi = lim[a1][c_1];
      float cr = lre[a2][c_2], ci = lim[a2][c_2];
      float dr = lre[a3][c_3], di = lim[a3][c_3];
      float apcr = ar + cr, apci = ai + ci;
      float amcr = ar - cr, amci = ai - ci;
      float bpdr = br + dr, bpdi = bi + di;
      float bmdr = br - dr, bmdi = bi - di;
      int ti = j * u;
      float y1r = amcr + bmdi, y1i = amci - bmdr;   // amc - i*bmd
      float y2r = apcr - bpdr, y2i = apci - bpdi;
      float y3r = amcr - bmdi, y3i = amci + bmdr;   // amc + i*bmd
      CMULW(y1r, y1i, ti); CMULW(y2r, y2i, 2 * ti); CMULW(y3r, y3i, 3 * ti);
      lre[a0][c_0] = apcr + bpdr;  lim[a0][c_0] = apci + bpdi;
      lre[a1][c_1] = y1r;          lim[a1][c_1] = y1i;
      lre[a2][c_2] = y2r;          lim[a2][c_2] = y2i;
      lre[a3][c_3] = y3r;          lim[a3][c_3] = y3i;
    }
  }
  __syncthreads();

  // C: fft out + mask + uk out (position p holds frequency rev4(p))
  const float* mk = mask + b * 65536;
  float* ukre = uk + b * 131072;
  float* ukim = ukre + 65536;
  for (int it = 0; it < 32; ++it) {
    int p = (it << 3) + rg;
    int f = rev4(p);
    int cc = (cl + p) & 31;
    float vr = lre[p][cc], vi = lim[p][cc];
    int gi = f * 256 + c0 + cl;
    pre[gi] = vr;  pim[gi] = vi;
    float m = mk[gi];
    float mvr = vr * m, mvi = vi * m;
    ukre[gi] = mvr;  ukim[gi] = mvi;
    lre[p][cc] = mvr;  lim[p][cc] = mvi;
  }

  // D: inverse DIT radix-4 (m = 4,16,64,256), conj twiddles
  #pragma unroll
  for (int s2 = 0; s2 < 4; ++s2) {
    __syncthreads();
    int lq = 2 * s2, qq = 1 << lq;
    int u = 64 >> lq;
    for (int kk = 0; kk < 8; ++kk) {
      int bf = (kk << 3) + rg;
      int j = bf & (qq - 1), g = bf >> lq;
      int base = (g << (lq + 2)) + j;
      int a0 = base, a1 = base + qq, a2 = base + 2 * qq, a3 = base + 3 * qq;
      int c_0 = (cl + a0) & 31, c_1 = (cl + a1) & 31,
          c_2 = (cl + a2) & 31, c_3 = (cl + a3) & 31;
      float s0r = lre[a0][c_0], s0i = lim[a0][c_0];
      float s1r = lre[a1][c_1], s1i = lim[a1][c_1];
      float s2r = lre[a2][c_2], s2i = lim[a2][c_2];
      float s3r = lre[a3][c_3], s3i = lim[a3][c_3];
      int ti = j * u;
      CMULWC(s1r, s1i, ti); CMULWC(s2r, s2i, 2 * ti); CMULWC(s3r, s3i, 3 * ti);
      float p0r = s0r + s2r, p0i = s0i + s2i;
      float m0r = s0r - s2r, m0i = s0i - s2i;
      float p1r = s1r + s3r, p1i = s1i + s3i;
      float m1r = s1r - s3r, m1i = s1i - s3i;
      lre[a0][c_0] = p0r + p1r;  lim[a0][c_0] = p0i + p1i;
      lre[a1][c_1] = m0r - m1i;  lim[a1][c_1] = m0i + m1r;   // m0 + i*m1
      lre[a2][c_2] = p0r - p1r;  lim[a2][c_2] = p0i - p1i;
      lre[a3][c_3] = m0r + m1i;  lim[a3][c_3] = m0i - m1r;   // m0 - i*m1
    }
  }
  __syncthreads();

  // E: write v (spatial rows)
  float* vre = vbuf + b * 131072;
  float* vim = vre + 65536;
  for (int it = 0; it < 32; ++it) {
    int r = (it << 3) + rg;
    int cc = (cl + r) & 31;
    vre[r * 256 + c0 + cl] = lre[r][cc];
    vim[r * 256 + c0 + cl] = lim[r][cc];
  }
}

// ============================================================================
// Row inverse FFT: radix-4 DIT (conj), rev4 gather, in-place on uifft slot,
// scale 1/65536, emit complex_abs. Block = 4 rows.
// ============================================================================
__global__ __launch_bounds__(256) void k_irow(float* __restrict__ uif,
                                              float* __restrict__ cabs,
                                              const float* __restrict__ ws) {
  __shared__ float re[4][264], im[4][264];
  const float* tw = ws + 131072;
  int rl = threadIdx.x >> 6, bf = threadIdx.x & 63;
  int line = blockIdx.x * 4 + rl;
  int b = line >> 8, h = line & 255;
  float* sre = uif + b * 131072 + h * 256;
  float* sim = sre + 65536;
  float* lre = re[rl];
  float* lim = im[rl];
  #pragma unroll
  for (int t2 = 0; t2 < 4; ++t2) {
    int p = t2 * 64 + bf;
    int q = rev4(p);
    lre[LMAP(p)] = sre[q];
    lim[LMAP(p)] = sim[q];
  }
  #pragma unroll
  for (int s2 = 0; s2 < 4; ++s2) {
    __syncthreads();
    int lq = 2 * s2, qq = 1 << lq;
    int j = bf & (qq - 1), g = bf >> lq;
    int base = (g << (lq + 2)) + j;
    int u = 64 >> lq;
    int a0 = base, a1 = base + qq, a2 = base + 2 * qq, a3 = base + 3 * qq;
    float s0r = lre[LMAP(a0)], s0i = lim[LMAP(a0)];
    float s1r = lre[LMAP(a1)], s1i = lim[LMAP(a1)];
    float s2r = lre[LMAP(a2)], s2i = lim[LMAP(a2)];
    float s3r = lre[LMAP(a3)], s3i = lim[LMAP(a3)];
    int ti = j * u;
    CMULWC(s1r, s1i, ti); CMULWC(s2r, s2i, 2 * ti); CMULWC(s3r, s3i, 3 * ti);
    float p0r = s0r + s2r, p0i = s0i + s2i;
    float m0r = s0r - s2r, m0i = s0i - s2i;
    float p1r = s1r + s3r, p1i = s1i + s3i;
    float m1r = s1r - s3r, m1i = s1i - s3i;
    lre[LMAP(a0)] = p0r + p1r;  lim[LMAP(a0)] = p0i + p1i;
    lre[LMAP(a1)] = m0r - m1i;  lim[LMAP(a1)] = m0i + m1r;   // m0 + i*m1
    lre[LMAP(a2)] = p0r - p1r;  lim[LMAP(a2)] = p0i - p1i;
    lre[LMAP(a3)] = m0r + m1i;  lim[LMAP(a3)] = m0i - m1r;   // m0 - i*m1
  }
  __syncthreads();
  const float scale = 1.0f / 65536.0f;
  float* ab = cabs + b * 65536 + h * 256;
  #pragma unroll
  for (int t2 = 0; t2 < 4; ++t2) {
    int p = t2 * 64 + bf;
    float vr = lre[LMAP(p)] * scale, vi = lim[LMAP(p)] * scale;
    sre[p] = vr;  sim[p] = vi;
    ab[p] = sqrtf(vr * vr + vi * vi);
  }
}

// ============================================================================
extern "C" void kernel_launch(void* const* d_in, const int* in_sizes, int n_in,
                              void* d_out, int out_size, void* d_ws, size_t ws_size,
                              hipStream_t stream) {
  const float* x      = (const float*)d_in[0];   // [64,1,256,256] f32
  const float* weight = (const float*)d_in[1];   // [1,1,256,256]  f32
  float* out = (float*)d_out;
  float* ws  = (float*)d_ws;

  float* uifft = out;                  // [64,2,256,256] (also v scratch)
  float* cabs  = out + 8388608;        // [64,1,256,256]
  float* mask  = out + 12582912;       // [64,1,256,256]
  float* fft   = out + 16777216;       // [64,2,256,256]
  float* uk    = out + 25165824;       // [64,2,256,256]

  // sub-key = jax.random.split(key(42))[1] (partitionable): block(0,1).
  unsigned sk0, sk1;
  tf2x32(0u, 42u, 0u, 1u, sk0, sk1);

  k_prep   <<<256, 256, 0, stream>>>(weight, ws);
  k_xbar   <<<1, 64, 0, stream>>>(ws);
  k_mask   <<<16384, 256, 0, stream>>>(ws, mask, sk0, sk1);
  k_fft_row<<<4096, 256, 0, stream>>>(x, fft, ws);
  k_colpass<<<512, 256, 0, stream>>>(fft, mask, uk, uifft, ws);
  k_irow   <<<4096, 256, 0, stream>>>(uifft, cabs, ws);
}